// Round 1
// baseline (22505.995 us; speedup 1.0000x reference)
//
#include <hip/hip_runtime.h>
#include <math.h>

// Problem constants (from reference): B=512, T=256, D=81, H=128
#define BB 512
#define TT 256
#define DD 81
#define HH 128

__device__ __forceinline__ float wave_sum(float v) {
#pragma unroll
    for (int off = 32; off > 0; off >>= 1) v += __shfl_xor(v, off, 64);
    return v;
}
__device__ __forceinline__ float wave_max(float v) {
#pragma unroll
    for (int off = 32; off > 0; off >>= 1) v = fmaxf(v, __shfl_xor(v, off, 64));
    return v;
}

// One block per batch row; T-loop inside (rows are independent — no grid sync).
// Each matvec output: one wave, split-K over 64 lanes (coalesced weight loads),
// butterfly reduce. Weights (600 KB fp32) stay L2-resident across all blocks.
__global__ __launch_bounds__(256, 2)
void encoder_kernel(const float* __restrict__ X,
                    const float* __restrict__ W1, const float* __restrict__ b1,
                    const float* __restrict__ W2, const float* __restrict__ b2,
                    const float* __restrict__ Wih, const float* __restrict__ Whh,
                    const float* __restrict__ bih, const float* __restrict__ bhh,
                    float* __restrict__ out_h, float* __restrict__ out_alpha) {
    const int b    = blockIdx.x;
    const int tid  = threadIdx.x;
    const int wave = tid >> 6;
    const int lane = tid & 63;

    __shared__ float hs[2 * HH];     // [h (128) ; c (128)] — matches concat(h, c)
    __shared__ float a1[HH];         // tanh(MLP1)
    __shared__ float e_s[DD];        // MLP2 out
    __shared__ float xw_s[DD];       // alpha * x_t
    __shared__ float gate_s[4 * HH]; // i,f,g,o pre-activations

    if (tid < 2 * HH) hs[tid] = 0.f;  // h0 = c0 = 0
    __syncthreads();

    const float* xb  = X + (size_t)b * TT * DD;
    float*       ohb = out_h + (size_t)b * TT * HH;
    float*       oab = out_alpha + (size_t)b * TT * DD;

    for (int t = 0; t < TT; ++t) {
        // ---- phase 1: a1 = tanh(hs @ W1.T + b1), W1 is [128, 256] row-major
        for (int j = wave; j < HH; j += 4) {
            const float* wr = W1 + (size_t)j * 256;
            float acc = 0.f;
#pragma unroll
            for (int it = 0; it < 4; ++it) {
                int k = lane + 64 * it;
                acc = fmaf(wr[k], hs[k], acc);
            }
            acc = wave_sum(acc);
            if (lane == 0) a1[j] = tanhf(acc + b1[j]);
        }
        __syncthreads();

        // ---- phase 2: e = a1 @ W2.T + b2, W2 is [81, 128] row-major
        for (int d = wave; d < DD; d += 4) {
            const float* wr = W2 + (size_t)d * HH;
            float acc = fmaf(wr[lane], a1[lane], 0.f);
            acc = fmaf(wr[lane + 64], a1[lane + 64], acc);
            acc = wave_sum(acc);
            if (lane == 0) e_s[d] = acc + b2[d];
        }
        __syncthreads();

        // ---- phase 3: alpha = softmax(e); xw = alpha * x_t; write alpha out
        if (wave == 0) {
            const float* xr = xb + (size_t)t * DD;
            float v0 = (lane < DD) ? e_s[lane] : -INFINITY;
            float v1 = (lane + 64 < DD) ? e_s[lane + 64] : -INFINITY;
            float m  = wave_max(fmaxf(v0, v1));
            float p0 = (lane < DD) ? expf(v0 - m) : 0.f;
            float p1 = (lane + 64 < DD) ? expf(v1 - m) : 0.f;
            float s  = wave_sum(p0 + p1);
            float inv = 1.f / s;
            if (lane < DD) {
                float al = p0 * inv;
                xw_s[lane] = al * xr[lane];
                oab[(size_t)t * DD + lane] = al;
            }
            if (lane + 64 < DD) {
                float al = p1 * inv;
                xw_s[lane + 64] = al * xr[lane + 64];
                oab[(size_t)t * DD + lane + 64] = al;
            }
        }
        __syncthreads();

        // ---- phase 4: gates = xw @ W_ih.T + b_ih + h @ W_hh.T + b_hh
        // W_ih [512, 81], W_hh [512, 128] row-major; gate order i,f,g,o
        for (int g = wave; g < 4 * HH; g += 4) {
            const float* wi = Wih + (size_t)g * DD;
            const float* wh = Whh + (size_t)g * HH;
            float acc = 0.f;
            if (lane < DD)      acc = fmaf(wi[lane],      xw_s[lane],      acc);
            if (lane + 64 < DD) acc = fmaf(wi[lane + 64], xw_s[lane + 64], acc);
            acc = fmaf(wh[lane],      hs[lane],      acc);
            acc = fmaf(wh[lane + 64], hs[lane + 64], acc);
            acc = wave_sum(acc);
            if (lane == 0) gate_s[g] = acc + bih[g] + bhh[g];
        }
        __syncthreads();

        // ---- phase 5: LSTM pointwise update
        if (tid < HH) {
            int u = tid;
            float gi = gate_s[u], gf = gate_s[u + HH];
            float gg = gate_s[u + 2 * HH], go = gate_s[u + 3 * HH];
            float si = 1.f / (1.f + expf(-gi));
            float sf = 1.f / (1.f + expf(-gf));
            float so = 1.f / (1.f + expf(-go));
            float cn = sf * hs[HH + u] + si * tanhf(gg);
            float hn = so * tanhf(cn);
            ohb[(size_t)t * HH + u] = hn;
            hs[u] = hn;
            hs[HH + u] = cn;
        }
        __syncthreads();
    }
}

extern "C" void kernel_launch(void* const* d_in, const int* in_sizes, int n_in,
                              void* d_out, int out_size, void* d_ws, size_t ws_size,
                              hipStream_t stream) {
    const float* X   = (const float*)d_in[0];
    const float* W1  = (const float*)d_in[1];
    const float* b1  = (const float*)d_in[2];
    const float* W2  = (const float*)d_in[3];
    const float* b2  = (const float*)d_in[4];
    const float* Wih = (const float*)d_in[5];
    const float* Whh = (const float*)d_in[6];
    const float* bih = (const float*)d_in[7];
    const float* bhh = (const float*)d_in[8];

    float* out_h     = (float*)d_out;                               // [512,256,128]
    float* out_alpha = (float*)d_out + (size_t)BB * TT * HH;        // [512,256,81]

    encoder_kernel<<<BB, 256, 0, stream>>>(X, W1, b1, W2, b2, Wih, Whh, bih, bhh,
                                           out_h, out_alpha);
}

// Round 2
// 2266.356 us; speedup vs baseline: 9.9305x; 9.9305x over previous
//
#include <hip/hip_runtime.h>
#include <math.h>

// B=512, T=256, D=81, H=128
#define BB 512
#define TT 256
#define DD 81
#define HH 128

// weight blob geometry (all float4 elements)
#define P1I 16            // phase1: K=256 split 4 ways -> 64 k/thread -> 16 float4 iters
#define P2I 8             // phase2: K=128 split 4 ways -> 32 k/thread -> 8 float4 iters
#define P4K 212           // 81 (Wih) + 128 (Whh) + 1 (bias) + 2 pad
#define P4I 53            // 212/4
#define BLOB1_ELEMS (P1I * 512)          // 8192 float4
#define BLOB2_ELEMS (P2I * 324)          // 2592 float4
#define BLOB4_ELEMS (P4I * 512)          // 27136 float4
#define BLOB1_OFF 0
#define BLOB2_OFF (BLOB1_ELEMS)
#define BLOB4_OFF (BLOB1_ELEMS + BLOB2_ELEMS)
#define WS_ELEMS  (BLOB1_ELEMS + BLOB2_ELEMS + BLOB4_ELEMS)

__device__ __forceinline__ float wave_sum(float v) {
#pragma unroll
    for (int off = 32; off > 0; off >>= 1) v += __shfl_xor(v, off, 64);
    return v;
}
__device__ __forceinline__ float wave_max(float v) {
#pragma unroll
    for (int off = 32; off > 0; off >>= 1) v = fmaxf(v, __shfl_xor(v, off, 64));
    return v;
}
__device__ __forceinline__ float fast_sig(float x) {
    return 1.f / (1.f + __expf(-x));
}
__device__ __forceinline__ float fast_tanh(float x) {
    // 1 - 2/(e^2x+1); correct at +/-inf
    return 1.f - 2.f / (__expf(2.f * x) + 1.f);
}

// ---------------- weight repack kernels (run each launch; ~600 KB) ----------------
// blob1[i*512 + j*4 + s] = W1[j][64s+4i .. +3]       (j<128, s<4, i<16)
__global__ void repack1(const float* __restrict__ W1, float4* __restrict__ dst) {
    int tid = blockIdx.x * blockDim.x + threadIdx.x;
    if (tid >= BLOB1_ELEMS) return;
    int i = tid >> 9, rem = tid & 511;
    int j = rem >> 2, s = rem & 3;
    dst[tid] = *(const float4*)(W1 + (size_t)j * 256 + 64 * s + 4 * i);
}
// blob2[i*324 + d*4 + s] = W2[d][32s+4i .. +3]       (d<81, s<4, i<8)
__global__ void repack2(const float* __restrict__ W2, float4* __restrict__ dst) {
    int tid = blockIdx.x * blockDim.x + threadIdx.x;
    if (tid >= BLOB2_ELEMS) return;
    int i = tid / 324, rem = tid - i * 324;
    int d = rem >> 2, s = rem & 3;
    dst[tid] = *(const float4*)(W2 + (size_t)d * 128 + 32 * s + 4 * i);
}
// blob4[i*512 + g] = cw(g, 4i..4i+3);  cw(g,k): k<81 Wih[g][k]; k<209 Whh[g][k-81];
//                                      k==209 bih[g]+bhh[g]; else 0
__global__ void repack4(const float* __restrict__ Wih, const float* __restrict__ Whh,
                        const float* __restrict__ bih, const float* __restrict__ bhh,
                        float4* __restrict__ dst) {
    int tid = blockIdx.x * blockDim.x + threadIdx.x;
    if (tid >= BLOB4_ELEMS) return;
    int i = tid >> 9, g = tid & 511;
    float v[4];
#pragma unroll
    for (int c = 0; c < 4; ++c) {
        int k = 4 * i + c;
        float x;
        if (k < 81)       x = Wih[(size_t)g * 81 + k];
        else if (k < 209) x = Whh[(size_t)g * 128 + (k - 81)];
        else if (k == 209) x = bih[g] + bhh[g];
        else              x = 0.f;
        v[c] = x;
    }
    dst[tid] = make_float4(v[0], v[1], v[2], v[3]);
}

// ---------------- main kernel: 256 blocks x 512 threads, 2 batch rows per block ----------------
__global__ __launch_bounds__(512, 2)
void encoder_kernel(const float* __restrict__ X,
                    const float* __restrict__ b1, const float* __restrict__ b2,
                    const float4* __restrict__ w1q, const float4* __restrict__ w2q,
                    const float4* __restrict__ w4q,
                    float* __restrict__ out_h, float* __restrict__ out_alpha) {
    const int tid  = threadIdx.x;
    const int wave = tid >> 6;
    const int lane = tid & 63;
    const int b0   = blockIdx.x * 2;        // rows b0, b0+1

    // packed {row0,row1} activations
    __shared__ alignas(16) float2 hs2[256];    // [0..127]=h, [128..255]=c
    __shared__ alignas(16) float2 a1_2[128];   // tanh(MLP1)
    __shared__ alignas(16) float2 e2[84];      // MLP2 out
    __shared__ alignas(16) float2 act2[P4K];   // [0..80]=xw, [81..208]=h, [209]={1,1}, pad 0
    __shared__ alignas(16) float2 gate2[512];  // gate preacts

    if (tid < 256) hs2[tid] = make_float2(0.f, 0.f);
    if (tid < 128) act2[81 + tid] = make_float2(0.f, 0.f);
    if (tid == 0) {
        act2[209] = make_float2(1.f, 1.f);
        act2[210] = make_float2(0.f, 0.f);
        act2[211] = make_float2(0.f, 0.f);
    }
    // per-thread resident biases
    const float breg1 = b1[tid >> 2];                       // phase1: j = tid>>2
    const float breg2 = (tid < 324) ? b2[tid >> 2] : 0.f;   // phase2: d = tid>>2
    __syncthreads();

    const float* xb0 = X + (size_t)b0 * TT * DD;
    const float* xb1 = X + (size_t)(b0 + 1) * TT * DD;
    float* oh0 = out_h + (size_t)b0 * TT * HH;
    float* oh1 = out_h + (size_t)(b0 + 1) * TT * HH;
    float* oa0 = out_alpha + (size_t)b0 * TT * DD;
    float* oa1 = out_alpha + (size_t)(b0 + 1) * TT * DD;

    const int s4 = tid & 3;   // split-K lane within quad

    for (int t = 0; t < TT; ++t) {
        // prefetch x_t for both rows (independent of recurrence chain)
        float xv0 = 0.f, xv1 = 0.f;
        if (wave < 2) {
            const float* xr = (wave == 0 ? xb0 : xb1) + (size_t)t * DD;
            xv0 = xr[lane];
            if (lane < DD - 64) xv1 = xr[lane + 64];
        }

        // ---- phase 1: a1 = tanh(W1 @ [h;c] + b1).  thread=(j=tid>>2, s=s4)
        {
            float acc0 = 0.f, acc1 = 0.f;
#pragma unroll 4
            for (int i = 0; i < P1I; ++i) {
                float4 w = w1q[i * 512 + tid];
                const float4* hp = (const float4*)&hs2[64 * s4 + 4 * i];
                float4 h01 = hp[0], h23 = hp[1];
                acc0 = fmaf(w.x, h01.x, acc0); acc1 = fmaf(w.x, h01.y, acc1);
                acc0 = fmaf(w.y, h01.z, acc0); acc1 = fmaf(w.y, h01.w, acc1);
                acc0 = fmaf(w.z, h23.x, acc0); acc1 = fmaf(w.z, h23.y, acc1);
                acc0 = fmaf(w.w, h23.z, acc0); acc1 = fmaf(w.w, h23.w, acc1);
            }
            acc0 += __shfl_xor(acc0, 1, 64); acc0 += __shfl_xor(acc0, 2, 64);
            acc1 += __shfl_xor(acc1, 1, 64); acc1 += __shfl_xor(acc1, 2, 64);
            if (s4 == 0)
                a1_2[tid >> 2] = make_float2(fast_tanh(acc0 + breg1),
                                             fast_tanh(acc1 + breg1));
        }
        __syncthreads();

        // ---- phase 2: e = W2 @ a1 + b2.  thread=(d=tid>>2, s=s4), tid<324
        if (tid < 324) {
            float acc0 = 0.f, acc1 = 0.f;
#pragma unroll
            for (int i = 0; i < P2I; ++i) {
                float4 w = w2q[i * 324 + tid];
                const float4* ap = (const float4*)&a1_2[32 * s4 + 4 * i];
                float4 a01 = ap[0], a23 = ap[1];
                acc0 = fmaf(w.x, a01.x, acc0); acc1 = fmaf(w.x, a01.y, acc1);
                acc0 = fmaf(w.y, a01.z, acc0); acc1 = fmaf(w.y, a01.w, acc1);
                acc0 = fmaf(w.z, a23.x, acc0); acc1 = fmaf(w.z, a23.y, acc1);
                acc0 = fmaf(w.w, a23.z, acc0); acc1 = fmaf(w.w, a23.w, acc1);
            }
            acc0 += __shfl_xor(acc0, 1, 64); acc0 += __shfl_xor(acc0, 2, 64);
            acc1 += __shfl_xor(acc1, 1, 64); acc1 += __shfl_xor(acc1, 2, 64);
            if (s4 == 0) e2[tid >> 2] = make_float2(acc0 + breg2, acc1 + breg2);
        }
        __syncthreads();

        // ---- phase 3: softmax + xw = alpha * x_t (wave r handles row r)
        if (wave < 2) {
            float ev0 = ((const float*)&e2[lane])[wave];
            float ev1 = (lane < DD - 64) ? ((const float*)&e2[lane + 64])[wave] : -INFINITY;
            float m  = wave_max(fmaxf(ev0, ev1));
            float p0 = __expf(ev0 - m);
            float p1 = (lane < DD - 64) ? __expf(ev1 - m) : 0.f;
            float inv = 1.f / wave_sum(p0 + p1);
            float* oa = (wave == 0) ? oa0 : oa1;
            float al0 = p0 * inv;
            ((float*)&act2[lane])[wave] = al0 * xv0;
            oa[(size_t)t * DD + lane] = al0;
            if (lane < DD - 64) {
                float al1 = p1 * inv;
                ((float*)&act2[lane + 64])[wave] = al1 * xv1;
                oa[(size_t)t * DD + lane + 64] = al1;
            }
        }
        __syncthreads();

        // ---- phase 4: gates = cw @ [xw; h; 1] (bias folded). thread g = tid.
        {
            float acc0 = 0.f, acc1 = 0.f;
#pragma unroll 4
            for (int i = 0; i < P4I; ++i) {
                float4 w = w4q[i * 512 + tid];
                const float4* ap = (const float4*)&act2[4 * i];   // broadcast
                float4 a01 = ap[0], a23 = ap[1];
                acc0 = fmaf(w.x, a01.x, acc0); acc1 = fmaf(w.x, a01.y, acc1);
                acc0 = fmaf(w.y, a01.z, acc0); acc1 = fmaf(w.y, a01.w, acc1);
                acc0 = fmaf(w.z, a23.x, acc0); acc1 = fmaf(w.z, a23.y, acc1);
                acc0 = fmaf(w.w, a23.z, acc0); acc1 = fmaf(w.w, a23.w, acc1);
            }
            gate2[tid] = make_float2(acc0, acc1);
        }
        __syncthreads();

        // ---- phase 5: LSTM pointwise; update h,c; write h out
        if (tid < 256) {
            int r = tid >> 7, u = tid & 127;
            float gi = ((const float*)&gate2[u])[r];
            float gf = ((const float*)&gate2[u + 128])[r];
            float gg = ((const float*)&gate2[u + 256])[r];
            float go = ((const float*)&gate2[u + 384])[r];
            float co = ((const float*)&hs2[128 + u])[r];
            float cn = fast_sig(gf) * co + fast_sig(gi) * fast_tanh(gg);
            float hn = fast_sig(go) * fast_tanh(cn);
            ((float*)&hs2[u])[r] = hn;
            ((float*)&hs2[128 + u])[r] = cn;
            ((float*)&act2[81 + u])[r] = hn;
            float* oh = r ? oh1 : oh0;
            oh[(size_t)t * HH + u] = hn;
        }
        __syncthreads();
    }
}

extern "C" void kernel_launch(void* const* d_in, const int* in_sizes, int n_in,
                              void* d_out, int out_size, void* d_ws, size_t ws_size,
                              hipStream_t stream) {
    const float* X   = (const float*)d_in[0];
    const float* W1  = (const float*)d_in[1];
    const float* b1  = (const float*)d_in[2];
    const float* W2  = (const float*)d_in[3];
    const float* b2  = (const float*)d_in[4];
    const float* Wih = (const float*)d_in[5];
    const float* Whh = (const float*)d_in[6];
    const float* bih = (const float*)d_in[7];
    const float* bhh = (const float*)d_in[8];

    if (ws_size < (size_t)WS_ELEMS * sizeof(float4)) return;  // need ~607 KB scratch

    float4* blob = (float4*)d_ws;
    float4* w1q = blob + BLOB1_OFF;
    float4* w2q = blob + BLOB2_OFF;
    float4* w4q = blob + BLOB4_OFF;

    repack1<<<(BLOB1_ELEMS + 255) / 256, 256, 0, stream>>>(W1, w1q);
    repack2<<<(BLOB2_ELEMS + 255) / 256, 256, 0, stream>>>(W2, w2q);
    repack4<<<(BLOB4_ELEMS + 255) / 256, 256, 0, stream>>>(Wih, Whh, bih, bhh, w4q);

    float* out_h     = (float*)d_out;                        // [512,256,128]
    float* out_alpha = (float*)d_out + (size_t)BB * TT * HH; // [512,256,81]

    encoder_kernel<<<BB / 2, 512, 0, stream>>>(X, b1, b2, w1q, w2q, w4q,
                                               out_h, out_alpha);
}

// Round 3
// 714.376 us; speedup vs baseline: 31.5044x; 3.1725x over previous
//
#include <hip/hip_runtime.h>
#include <math.h>

// B=512, T=256, D=81, H=128
#define BB 512
#define TT 256
#define DD 81
#define HH 128

typedef _Float16 half8 __attribute__((ext_vector_type(8)));
typedef float    f32x4 __attribute__((ext_vector_type(4)));

// ---- d_ws blob geometry (float4 units) ----
// [0, 5632): LDS image = W1 frag chunks (4096) + W2 frag chunks (1536)
// [5632, 5632+14336): W4 register fragments (28 frags x 512 threads)
#define BLOB_LDS_ELEMS 5632
#define BLOB_W4_ELEMS  14336
#define BLOB_W4_OFF    BLOB_LDS_ELEMS
#define WS_ELEMS       (BLOB_LDS_ELEMS + BLOB_W4_ELEMS)

// ---- LDS layout (bytes) ----
#define W1_OFF   0        // 64 KB: 64 chunks (ntile 0..7 x ktile 0..7) x 1 KB
#define W2_OFF   65536    // 24 KB: 24 chunks (ntile 0..5 x ktile 0..3) x 1 KB
#define HS_OFF   90112    // [2][256] fp16  [h;c], row stride 512 B
#define ACT_OFF  91136    // [2][224] fp16  [xw(81); h(128); 1; 0-pad], stride 448 B
#define A1_OFF   92032    // [2][128] fp16, row stride 256 B
#define E_OFF    92544    // [2][96] f32
#define GATE_OFF 93312    // [2][512] f32
#define C_OFF    97408    // [2][128] f32
#define LDS_BYTES 98432

__device__ __forceinline__ float wave_sum(float v) {
#pragma unroll
    for (int off = 32; off > 0; off >>= 1) v += __shfl_xor(v, off, 64);
    return v;
}
__device__ __forceinline__ float wave_max(float v) {
#pragma unroll
    for (int off = 32; off > 0; off >>= 1) v = fmaxf(v, __shfl_xor(v, off, 64));
    return v;
}
__device__ __forceinline__ float fast_sig(float x)  { return 1.f / (1.f + __expf(-x)); }
__device__ __forceinline__ float fast_tanh(float x) { return 1.f - 2.f / (__expf(2.f * x) + 1.f); }

__device__ __forceinline__ float4 pack8h(const float* v) {
    union { float4 f4; _Float16 h[8]; } u;
#pragma unroll
    for (int c = 0; c < 8; ++c) u.h[c] = (_Float16)v[c];
    return u.f4;
}

// ---------------- repack kernels ----------------
// LDS image: B-fragment chunks, 1 KB each, lane l's 16 B at chunk + l*16.
// Fragment content for chunk(nt,kt), lane l: W[n][kb..kb+7] fp16,
//   n = 16*nt + (l&15), kb = 32*kt + (l>>4)*8   (B[k][n] layout: n=lane&15, k=quad*8+j)
__global__ void repack_lds_blob(const float* __restrict__ W1, const float* __restrict__ W2,
                                float4* __restrict__ dst) {
    int tid = blockIdx.x * blockDim.x + threadIdx.x;
    if (tid >= BLOB_LDS_ELEMS) return;
    float v[8];
    if (tid < 4096) {                      // W1 [128][256]
        int c = tid >> 6, l = tid & 63;
        int nt = c >> 3, kt = c & 7;
        int n = 16 * nt + (l & 15);
        int kb = 32 * kt + ((l >> 4) << 3);
#pragma unroll
        for (int c2 = 0; c2 < 8; ++c2) v[c2] = W1[(size_t)n * 256 + kb + c2];
    } else {                               // W2 [81][128], pad n>=81 with 0
        int idx = tid - 4096;
        int c = idx >> 6, l = idx & 63;
        int nt = c >> 2, kt = c & 3;
        int n = 16 * nt + (l & 15);
        int kb = 32 * kt + ((l >> 4) << 3);
#pragma unroll
        for (int c2 = 0; c2 < 8; ++c2)
            v[c2] = (n < 81) ? W2[(size_t)n * 128 + kb + c2] : 0.f;
    }
    dst[tid] = pack8h(v);
}

// W4 register fragments: frag f = j*7+kt (j=n-subtile 0..3, kt=0..6), thread r=w*64+l.
// n = 64*w + 16*j + (l&15); k = 32*kt + (l>>4)*8 + c over fused K:
//   k<81: Wih[n][k]; k<209: Whh[n][k-81]; k==209: bih[n]+bhh[n]; else 0.
__global__ void repack_w4(const float* __restrict__ Wih, const float* __restrict__ Whh,
                          const float* __restrict__ bih, const float* __restrict__ bhh,
                          float4* __restrict__ dst) {
    int tid = blockIdx.x * blockDim.x + threadIdx.x;
    if (tid >= BLOB_W4_ELEMS) return;
    int f = tid >> 9, r = tid & 511;
    int w = r >> 6, l = r & 63;
    int j = f / 7, kt = f - 7 * j;
    int n = 64 * w + 16 * j + (l & 15);
    int kb = 32 * kt + ((l >> 4) << 3);
    float v[8];
#pragma unroll
    for (int c = 0; c < 8; ++c) {
        int k = kb + c;
        float x;
        if (k < 81)        x = Wih[(size_t)n * 81 + k];
        else if (k < 209)  x = Whh[(size_t)n * 128 + (k - 81)];
        else if (k == 209) x = bih[n] + bhh[n];
        else               x = 0.f;
        v[c] = x;
    }
    dst[tid] = pack8h(v);
}

// ---------------- main kernel: 256 blocks x 512 threads, 2 rows/block ----------------
__global__ __launch_bounds__(512, 2)
void encoder_kernel(const float* __restrict__ X,
                    const float* __restrict__ b1, const float* __restrict__ b2,
                    const float4* __restrict__ wlds, const float4* __restrict__ w4q,
                    float* __restrict__ out_h, float* __restrict__ out_alpha) {
    const int tid = threadIdx.x;
    const int w   = tid >> 6;
    const int l   = tid & 63;
    const int b0  = blockIdx.x * 2;

    __shared__ __align__(16) unsigned char lds[LDS_BYTES];

    // stage W1/W2 fragment chunks into LDS (90112 B = 11 x 512 float4)
#pragma unroll
    for (int i = 0; i < 11; ++i)
        ((float4*)lds)[i * 512 + tid] = wlds[i * 512 + tid];

    // load resident W4 B-fragments (112 VGPRs)
    half8 wf[4][7];
#pragma unroll
    for (int j = 0; j < 4; ++j)
#pragma unroll
        for (int kt = 0; kt < 7; ++kt) {
            float4 t = w4q[(j * 7 + kt) * 512 + tid];
            wf[j][kt] = *(half8*)&t;
        }

    // per-thread biases (used by lanes l<16 only)
    const float breg1 = b1[16 * w + (l & 15)];
    const int   n2    = 16 * w + (l & 15);
    const float breg2 = (n2 < 81) ? b2[n2] : 0.f;

    // init state
    if (tid < 512) ((unsigned short*)(lds + HS_OFF))[tid] = 0;   // h,c fp16 = 0
    if (tid < 448) {                                             // act4: zeros, [209]=1
        int r = tid / 224, i = tid - r * 224;
        ((_Float16*)(lds + ACT_OFF))[r * 224 + i] = (i == 209) ? (_Float16)1.0f : (_Float16)0.0f;
    }
    if (tid < 256) ((float*)(lds + C_OFF))[tid] = 0.f;           // c fp32 = 0
    __syncthreads();

#pragma unroll 1
    for (int t = 0; t < TT; ++t) {
        // prefetch x_t (waves 0,1 = rows 0,1)
        float xv0 = 0.f, xv1 = 0.f;
        if (w < 2) {
            const float* xr = X + ((size_t)(b0 + w) * TT + t) * DD;
            xv0 = xr[l];
            if (l < DD - 64) xv1 = xr[l + 64];
        }

        // ---- phase 1: a1 = tanh(W1 @ [h;c] + b1); wave w owns n-tile w
        {
            const unsigned offA = (l & 1) * 512 + (l >> 4) * 16;
            f32x4 ae = {0.f, 0.f, 0.f, 0.f}, ao = {0.f, 0.f, 0.f, 0.f};
#pragma unroll
            for (int kt = 0; kt < 8; ++kt) {
                half8 a = *(const half8*)(lds + HS_OFF + offA + kt * 64);
                half8 b = *(const half8*)(lds + W1_OFF + (w * 8 + kt) * 1024 + l * 16);
                if (kt & 1) ao = __builtin_amdgcn_mfma_f32_16x16x32_f16(a, b, ao, 0, 0, 0);
                else        ae = __builtin_amdgcn_mfma_f32_16x16x32_f16(a, b, ae, 0, 0, 0);
            }
            if (l < 16) {
                _Float16* a1f = (_Float16*)(lds + A1_OFF);
                float v0 = fast_tanh(ae[0] + ao[0] + breg1);
                float v1 = fast_tanh(ae[1] + ao[1] + breg1);
                a1f[16 * w + l]       = (_Float16)v0;
                a1f[128 + 16 * w + l] = (_Float16)v1;
            }
        }
        __syncthreads();

        // ---- phase 2: e = W2 @ a1 + b2; waves 0..5
        if (w < 6) {
            const unsigned offA = (l & 1) * 256 + (l >> 4) * 16;
            f32x4 ae = {0.f, 0.f, 0.f, 0.f}, ao = {0.f, 0.f, 0.f, 0.f};
#pragma unroll
            for (int kt = 0; kt < 4; ++kt) {
                half8 a = *(const half8*)(lds + A1_OFF + offA + kt * 64);
                half8 b = *(const half8*)(lds + W2_OFF + (w * 4 + kt) * 1024 + l * 16);
                if (kt & 1) ao = __builtin_amdgcn_mfma_f32_16x16x32_f16(a, b, ao, 0, 0, 0);
                else        ae = __builtin_amdgcn_mfma_f32_16x16x32_f16(a, b, ae, 0, 0, 0);
            }
            if (l < 16) {
                float* es = (float*)(lds + E_OFF);
                es[16 * w + l]      = ae[0] + ao[0] + breg2;
                es[96 + 16 * w + l] = ae[1] + ao[1] + breg2;
            }
        }
        __syncthreads();

        // ---- phase 3: softmax + xw; wave r handles row r
        if (w < 2) {
            const float* er = (const float*)(lds + E_OFF) + w * 96;
            float ev0 = er[l];
            float ev1 = (l < DD - 64) ? er[l + 64] : -INFINITY;
            float m  = wave_max(fmaxf(ev0, ev1));
            float p0 = __expf(ev0 - m);
            float p1 = (l < DD - 64) ? __expf(ev1 - m) : 0.f;
            float inv = 1.f / wave_sum(p0 + p1);
            _Float16* act = (_Float16*)(lds + ACT_OFF) + w * 224;
            float* oa = out_alpha + ((size_t)(b0 + w) * TT + t) * DD;
            float al0 = p0 * inv;
            act[l] = (_Float16)(al0 * xv0);
            oa[l] = al0;
            if (l < DD - 64) {
                float al1 = p1 * inv;
                act[l + 64] = (_Float16)(al1 * xv1);
                oa[l + 64] = al1;
            }
        }
        __syncthreads();

        // ---- phase 4: gates = [xw;h;1] @ W4^T (bias folded); wave w owns gates [64w,64w+64)
        {
            const unsigned offA = (l & 1) * 448 + (l >> 4) * 16;
            half8 a4[7];
#pragma unroll
            for (int kt = 0; kt < 7; ++kt)
                a4[kt] = *(const half8*)(lds + ACT_OFF + offA + kt * 64);
            f32x4 g0 = {0.f,0.f,0.f,0.f}, g1 = g0, g2 = g0, g3 = g0;
#pragma unroll
            for (int kt = 0; kt < 7; ++kt) {
                g0 = __builtin_amdgcn_mfma_f32_16x16x32_f16(a4[kt], wf[0][kt], g0, 0, 0, 0);
                g1 = __builtin_amdgcn_mfma_f32_16x16x32_f16(a4[kt], wf[1][kt], g1, 0, 0, 0);
                g2 = __builtin_amdgcn_mfma_f32_16x16x32_f16(a4[kt], wf[2][kt], g2, 0, 0, 0);
                g3 = __builtin_amdgcn_mfma_f32_16x16x32_f16(a4[kt], wf[3][kt], g3, 0, 0, 0);
            }
            if (l < 16) {
                float* gs = (float*)(lds + GATE_OFF);
                gs[       64 * w      + l] = g0[0]; gs[512 + 64 * w      + l] = g0[1];
                gs[       64 * w + 16 + l] = g1[0]; gs[512 + 64 * w + 16 + l] = g1[1];
                gs[       64 * w + 32 + l] = g2[0]; gs[512 + 64 * w + 32 + l] = g2[1];
                gs[       64 * w + 48 + l] = g3[0]; gs[512 + 64 * w + 48 + l] = g3[1];
            }
        }
        __syncthreads();

        // ---- phase 5: LSTM pointwise; update h,c
        if (tid < 256) {
            int r = tid >> 7, u = tid & 127;
            const float* gs = (const float*)(lds + GATE_OFF) + r * 512;
            float gi = gs[u], gf = gs[u + 128], gg = gs[u + 256], go = gs[u + 384];
            float* cs = (float*)(lds + C_OFF) + r * 128;
            float cn = fast_sig(gf) * cs[u] + fast_sig(gi) * fast_tanh(gg);
            float hn = fast_sig(go) * fast_tanh(cn);
            cs[u] = cn;
            _Float16 hh = (_Float16)hn, ch = (_Float16)cn;
            _Float16* hsr = (_Float16*)(lds + HS_OFF) + r * 256;
            hsr[u] = hh; hsr[128 + u] = ch;
            ((_Float16*)(lds + ACT_OFF))[r * 224 + 81 + u] = hh;
            out_h[((size_t)(b0 + r) * TT + t) * HH + u] = hn;
        }
        __syncthreads();
    }
}

extern "C" void kernel_launch(void* const* d_in, const int* in_sizes, int n_in,
                              void* d_out, int out_size, void* d_ws, size_t ws_size,
                              hipStream_t stream) {
    const float* X   = (const float*)d_in[0];
    const float* W1  = (const float*)d_in[1];
    const float* b1  = (const float*)d_in[2];
    const float* W2  = (const float*)d_in[3];
    const float* b2  = (const float*)d_in[4];
    const float* Wih = (const float*)d_in[5];
    const float* Whh = (const float*)d_in[6];
    const float* bih = (const float*)d_in[7];
    const float* bhh = (const float*)d_in[8];

    if (ws_size < (size_t)WS_ELEMS * sizeof(float4)) return;  // ~320 KB scratch

    float4* blob = (float4*)d_ws;
    float4* wlds = blob;
    float4* w4q  = blob + BLOB_W4_OFF;

    repack_lds_blob<<<(BLOB_LDS_ELEMS + 255) / 256, 256, 0, stream>>>(W1, W2, wlds);
    repack_w4<<<(BLOB_W4_ELEMS + 255) / 256, 256, 0, stream>>>(Wih, Whh, bih, bhh, w4q);

    float* out_h     = (float*)d_out;                        // [512,256,128]
    float* out_alpha = (float*)d_out + (size_t)BB * TT * HH; // [512,256,81]

    encoder_kernel<<<BB / 2, 512, 0, stream>>>(X, b1, b2, wlds, w4q, out_h, out_alpha);
}